// Round 2
// baseline (1229.072 us; speedup 1.0000x reference)
//
#include <hip/hip_runtime.h>
#include <math.h>
#include <limits.h>

#define HH 1280
#define WW 1920
#define OUT_H 427
#define OUT_W 640
#define SENT 0x7fffffff

// ---------------- scatter: project points, atomicAdd depth ----------------
// NOTE: must reproduce XLA CPU's dot lowering bit-exactly: plain mul/add
// (no FMA contraction), ascending-k accumulation, translation added after.
__global__ void scatter_k(const float* __restrict__ pts,
                          const float* __restrict__ pose,
                          const float* __restrict__ extr,
                          const float* __restrict__ intr,
                          float* __restrict__ depth, int N) {
    #pragma clang fp contract(off)
    int t = blockIdx.x * blockDim.x + threadIdx.x;
    int b = blockIdx.y;
    if (t >= N) return;
    const float* p = pts + ((long)b * N + t) * 3;
    float x = p[0], y = p[1], z = p[2];
    const float* P = pose + b * 16;
    const float* E = extr + b * 16;
    const float* K = intr + b * 9;
    // pts_world = p @ pose[:3,:3].T + pose[:3,3]   (ascending k, no fma)
    float wx = ((x*P[0] + y*P[1]) + z*P[2]) + P[3];
    float wy = ((x*P[4] + y*P[5]) + z*P[6]) + P[7];
    float wz = ((x*P[8] + y*P[9]) + z*P[10]) + P[11];
    // cam = pts_world @ extrinsic[:3,:3].T + extrinsic[:3,3]
    float cx = ((wx*E[0] + wy*E[1]) + wz*E[2]) + E[3];
    float cy = ((wx*E[4] + wy*E[5]) + wz*E[6]) + E[7];
    float cz = ((wx*E[8] + wy*E[9]) + wz*E[10]) + E[11];
    // proj = cam @ intrinsic.T
    float px = (cx*K[0] + cy*K[1]) + cz*K[2];
    float py = (cx*K[3] + cy*K[4]) + cz*K[5];
    float pz = (cx*K[6] + cy*K[7]) + cz*K[8];
    float u = px / pz, v = py / pz;
    int r = (int)floorf(v), c = (int)floorf(u);
    if (r >= 0 && r < HH && c >= 0 && c < WW) {
        float dv = sqrtf((x*x + y*y) + z*z);
        atomicAdd(depth + ((long)b * HH + r) * WW + c, dv);
    }
}

// ---------------- init nearest: self if valid else sentinel ----------------
__global__ void init_k(const float* __restrict__ depth, int* __restrict__ nr) {
    int j = blockIdx.x * blockDim.x + threadIdx.x;
    int i = blockIdx.y, b = blockIdx.z;
    if (j >= WW) return;
    long t = ((long)b * HH + i) * WW + j;
    nr[t] = (depth[t] != 0.0f) ? ((i << 11) | j) : SENT;
}

// ---------------- one JFA directional pass ----------------
__global__ void jfa_k(const int* __restrict__ in, int* __restrict__ out,
                      int dy, int dx) {
    int j = blockIdx.x * blockDim.x + threadIdx.x;
    int i = blockIdx.y, b = blockIdx.z;
    if (j >= WW) return;
    long base = (long)b * HH * WW;
    long t = base + (long)i * WW + j;
    int cur = in[t];
    int sr = i - dy, sc = j - dx;
    int cand = SENT;
    if (sr >= 0 && sr < HH && sc >= 0 && sc < WW)
        cand = in[base + (long)sr * WW + sc];
    if (cand != SENT) {
        int cr = cand >> 11, cc = cand & 2047;
        int dr = i - cr, dc = j - cc;
        int d = dr * dr + dc * dc;
        int dcur;
        if (cur == SENT) dcur = INT_MAX;
        else {
            int ar = i - (cur >> 11), ac = j - (cur & 2047);
            dcur = ar * ar + ac * ac;
        }
        if (d < dcur) cur = cand;
    }
    out[t] = cur;
}

// ------- compose filled/dist on the fly + horizontal resize (W 1920->640) -------
__global__ void hresize_k(const float* __restrict__ depth,
                          const int* __restrict__ nr,
                          float* __restrict__ tmp) {
    int ow = blockIdx.x * blockDim.x + threadIdx.x;
    int i = blockIdx.y, b = blockIdx.z;
    if (ow >= OUT_W) return;
    const float inv = 3.0f;  // 1920/640
    float sf = (ow + 0.5f) * inv - 0.5f;
    int i0 = (int)ceilf(sf - inv);
    float a0 = 0.f, a1 = 0.f, wsum = 0.f;
    long rowbase = ((long)b * HH + i) * WW;
    long imgbase = (long)b * HH * WW;
    for (int k = 0; k < 7; ++k) {
        int iw = i0 + k;
        if (iw < 0 || iw >= WW) continue;
        float wgt = 1.0f - fabsf(sf - (float)iw) / inv;
        if (wgt <= 0.0f) continue;
        float dv = depth[rowbase + iw];
        float f, dist;
        if (dv != 0.0f) { f = dv; dist = 0.0f; }
        else {
            int nn = nr[rowbase + iw];
            int rr, cc;
            if (nn == SENT) { rr = HH - 1; cc = WW - 1; }  // clip(BIG) path
            else { rr = nn >> 11; cc = nn & 2047; }
            f = depth[imgbase + (long)rr * WW + cc];
            float drr = (float)i - (float)rr, dcc = (float)iw - (float)cc;
            dist = sqrtf(drr * drr + dcc * dcc);
        }
        a0 += wgt * f; a1 += wgt * dist; wsum += wgt;
    }
    long o = (((long)b * 2 + 0) * HH + i) * OUT_W + ow;
    tmp[o] = a0 / wsum;
    tmp[o + (long)HH * OUT_W] = a1 / wsum;
}

// ---------------- vertical resize (H 1280->427) ----------------
__global__ void vresize_k(const float* __restrict__ tmp, float* __restrict__ out) {
    int ow = blockIdx.x * blockDim.x + threadIdx.x;
    int oh = blockIdx.y, bc = blockIdx.z;  // bc = b*2 + ch
    if (ow >= OUT_W) return;
    const float inv = (float)(1280.0 / 427.0);
    float sf = (oh + 0.5f) * inv - 0.5f;
    int i0 = (int)ceilf(sf - inv);
    float acc = 0.f, wsum = 0.f;
    const float* src = tmp + (long)bc * HH * OUT_W;
    for (int k = 0; k < 7; ++k) {
        int ih = i0 + k;
        if (ih < 0 || ih >= HH) continue;
        float wgt = 1.0f - fabsf(sf - (float)ih) / inv;
        if (wgt <= 0.0f) continue;
        acc += wgt * src[(long)ih * OUT_W + ow];
        wsum += wgt;
    }
    out[((long)bc * OUT_H + oh) * OUT_W + ow] = acc / wsum;
}

extern "C" void kernel_launch(void* const* d_in, const int* in_sizes, int n_in,
                              void* d_out, int out_size, void* d_ws, size_t ws_size,
                              hipStream_t stream) {
    const float* pts  = (const float*)d_in[0];
    const float* pose = (const float*)d_in[1];
    const float* extr = (const float*)d_in[2];
    const float* intr = (const float*)d_in[3];
    int B = in_sizes[1] / 16;
    int N = in_sizes[0] / (3 * B);

    char* ws = (char*)d_ws;
    size_t imgSz = (size_t)B * HH * WW;         // elements per full canvas set
    float* depth = (float*)ws;                  // B*H*W f32
    int*   nearA = (int*)(ws + imgSz * 4);      // B*H*W i32
    int*   nearB = (int*)(ws + imgSz * 8);      // B*H*W i32
    float* tmp   = (float*)(ws + imgSz * 12);   // B*2*H*OUT_W f32

    hipMemsetAsync(depth, 0, imgSz * sizeof(float), stream);

    dim3 bs(256);
    scatter_k<<<dim3((N + 255) / 256, B), bs, 0, stream>>>(pts, pose, extr, intr, depth, N);

    dim3 g2((WW + 255) / 256, HH, B);
    init_k<<<g2, bs, 0, stream>>>(depth, nearA);

    const int steps[12] = {1, 1024, 512, 256, 128, 64, 32, 16, 8, 4, 2, 1};
    int* cur = nearA; int* nxt = nearB;
    for (int s = 0; s < 12; ++s) {
        int k = steps[s];
        for (int dy = -k; dy <= k; dy += k) {
            for (int dx = -k; dx <= k; dx += k) {
                if (dy == 0 && dx == 0) continue;
                jfa_k<<<g2, bs, 0, stream>>>(cur, nxt, dy, dx);
                int* t2 = cur; cur = nxt; nxt = t2;
            }
        }
    }

    hresize_k<<<dim3((OUT_W + 255) / 256, HH, B), bs, 0, stream>>>(depth, cur, tmp);
    vresize_k<<<dim3((OUT_W + 255) / 256, OUT_H, B * 2), bs, 0, stream>>>(tmp, (float*)d_out);
}

// Round 3
// 960.804 us; speedup vs baseline: 1.2792x; 1.2792x over previous
//
#include <hip/hip_runtime.h>
#include <math.h>
#include <limits.h>

#define HH 1280
#define WW 1920
#define OUT_H 427
#define OUT_W 640
#define SENT 0x7fffffff

// ---------------- scatter: project points, atomicAdd depth ----------------
// Reproduces XLA CPU dot lowering bit-exactly: plain mul/add (no FMA),
// ascending-k accumulation, translation added after.
__global__ void scatter_k(const float* __restrict__ pts,
                          const float* __restrict__ pose,
                          const float* __restrict__ extr,
                          const float* __restrict__ intr,
                          float* __restrict__ depth, int N) {
    #pragma clang fp contract(off)
    int t = blockIdx.x * blockDim.x + threadIdx.x;
    int b = blockIdx.y;
    if (t >= N) return;
    const float* p = pts + ((long)b * N + t) * 3;
    float x = p[0], y = p[1], z = p[2];
    const float* P = pose + b * 16;
    const float* E = extr + b * 16;
    const float* K = intr + b * 9;
    float wx = ((x*P[0] + y*P[1]) + z*P[2]) + P[3];
    float wy = ((x*P[4] + y*P[5]) + z*P[6]) + P[7];
    float wz = ((x*P[8] + y*P[9]) + z*P[10]) + P[11];
    float cx = ((wx*E[0] + wy*E[1]) + wz*E[2]) + E[3];
    float cy = ((wx*E[4] + wy*E[5]) + wz*E[6]) + E[7];
    float cz = ((wx*E[8] + wy*E[9]) + wz*E[10]) + E[11];
    float px = (cx*K[0] + cy*K[1]) + cz*K[2];
    float py = (cx*K[3] + cy*K[4]) + cz*K[5];
    float pz = (cx*K[6] + cy*K[7]) + cz*K[8];
    float u = px / pz, v = py / pz;
    int r = (int)floorf(v), c = (int)floorf(u);
    if (r >= 0 && r < HH && c >= 0 && c < WW) {
        float dv = sqrtf((x*x + y*y) + z*z);
        atomicAdd(depth + ((long)b * HH + r) * WW + c, dv);
    }
}

// ---------------- init nearest: self if valid else sentinel ----------------
__global__ void init_k(const float* __restrict__ depth, int* __restrict__ nr) {
    int j = blockIdx.x * blockDim.x + threadIdx.x;
    int i = blockIdx.y, b = blockIdx.z;
    if (j >= WW) return;
    long t = ((long)b * HH + i) * WW + j;
    nr[t] = (depth[t] != 0.0f) ? ((i << 11) | j) : SENT;
}

// ---------------- fused-JFA helpers (bit-exact recomputation fusion) -------
__device__ __forceinline__ int d2f(int pi, int pj, int s) {
    int dr = pi - (s >> 11);
    int dc = pj - (s & 2047);
    return dr * dr + dc * dc;
}
// sequential semantics: take cand iff cand!=SENT and d(cand) < d(cur), strict
__device__ __forceinline__ int pick(int pi, int pj, int cur, int cand) {
    if (cand != SENT) {
        int dn = d2f(pi, pj, cand);
        int dc_ = (cur == SENT) ? INT_MAX : d2f(pi, pj, cur);
        if (dn < dc_) return cand;
    }
    return cur;
}
__device__ __forceinline__ int ldq(const int* __restrict__ im, int i, int j) {
    return (i >= 0 && i < HH && j >= 0 && j < WW) ? im[i * WW + j] : SENT;
}
// value at q after pass (dy,-k), i.e. out1[q] = pick_q(in[q], in[q_i-dy, q_j+k]);
// returns SENT if q itself is outside the image (candidate skipped upstream)
__device__ __forceinline__ int out1q(const int* __restrict__ im,
                                     int qi, int qj, int dy, int k) {
    if (qi < 0 || qi >= HH || qj < 0 || qj >= WW) return SENT;
    int cur = im[qi * WW + qj];
    int cand = ldq(im, qi - dy, qj + k);
    return pick(qi, qj, cur, cand);
}

// ---- fused group of 3 passes with fixed dy: (dy,-k),(dy,0),(dy,+k) in order ----
__global__ void jfa3_k(const int* __restrict__ in, int* __restrict__ out,
                       int dy, int k) {
    int j = blockIdx.x * blockDim.x + threadIdx.x;
    int i = blockIdx.y, b = blockIdx.z;
    if (j >= WW) return;
    const int* im = in + (long)b * HH * WW;
    // out2[p] = pick_p(out1[p], out1[p_i-dy, p_j])
    int o1_p = out1q(im, i,      j, dy, k);
    int o1_m = out1q(im, i - dy, j, dy, k);
    int o2_p = pick(i, j, o1_p, o1_m);
    // out2 at q=(i-dy, j-k), the candidate position of pass 3
    int o2_q;
    {
        int qi = i - dy, qj = j - k;
        if (qi < 0 || qi >= HH || qj < 0 || qj >= WW) o2_q = SENT;
        else {
            int a0 = out1q(im, qi,      qj, dy, k);
            int a1 = out1q(im, qi - dy, qj, dy, k);
            o2_q = pick(qi, qj, a0, a1);
        }
    }
    int o3 = pick(i, j, o2_p, o2_q);
    out[(long)b * HH * WW + (long)i * WW + j] = o3;
}

// ---- fused group of 2 passes with dy=0: (0,-k),(0,+k) in order ----
__global__ void jfa2_k(const int* __restrict__ in, int* __restrict__ out, int k) {
    int j = blockIdx.x * blockDim.x + threadIdx.x;
    int i = blockIdx.y, b = blockIdx.z;
    if (j >= WW) return;
    const int* im = in + (long)b * HH * WW;
    int o1_p = out1q(im, i, j,     0, k);
    int o1_m = out1q(im, i, j - k, 0, k);
    int o2 = pick(i, j, o1_p, o1_m);
    out[(long)b * HH * WW + (long)i * WW + j] = o2;
}

// ------- compose filled/dist on the fly + horizontal resize (W 1920->640) -------
__global__ void hresize_k(const float* __restrict__ depth,
                          const int* __restrict__ nr,
                          float* __restrict__ tmp) {
    int ow = blockIdx.x * blockDim.x + threadIdx.x;
    int i = blockIdx.y, b = blockIdx.z;
    if (ow >= OUT_W) return;
    const float inv = 3.0f;  // 1920/640
    float sf = (ow + 0.5f) * inv - 0.5f;
    int i0 = (int)ceilf(sf - inv);
    float a0 = 0.f, a1 = 0.f, wsum = 0.f;
    long rowbase = ((long)b * HH + i) * WW;
    long imgbase = (long)b * HH * WW;
    for (int k = 0; k < 7; ++k) {
        int iw = i0 + k;
        if (iw < 0 || iw >= WW) continue;
        float wgt = 1.0f - fabsf(sf - (float)iw) / inv;
        if (wgt <= 0.0f) continue;
        float dv = depth[rowbase + iw];
        float f, dist;
        if (dv != 0.0f) { f = dv; dist = 0.0f; }
        else {
            int nn = nr[rowbase + iw];
            int rr, cc;
            if (nn == SENT) { rr = HH - 1; cc = WW - 1; }  // clip(BIG) path
            else { rr = nn >> 11; cc = nn & 2047; }
            f = depth[imgbase + (long)rr * WW + cc];
            float drr = (float)i - (float)rr, dcc = (float)iw - (float)cc;
            dist = sqrtf(drr * drr + dcc * dcc);
        }
        a0 += wgt * f; a1 += wgt * dist; wsum += wgt;
    }
    long o = (((long)b * 2 + 0) * HH + i) * OUT_W + ow;
    tmp[o] = a0 / wsum;
    tmp[o + (long)HH * OUT_W] = a1 / wsum;
}

// ---------------- vertical resize (H 1280->427) ----------------
__global__ void vresize_k(const float* __restrict__ tmp, float* __restrict__ out) {
    int ow = blockIdx.x * blockDim.x + threadIdx.x;
    int oh = blockIdx.y, bc = blockIdx.z;  // bc = b*2 + ch
    if (ow >= OUT_W) return;
    const float inv = (float)(1280.0 / 427.0);
    float sf = (oh + 0.5f) * inv - 0.5f;
    int i0 = (int)ceilf(sf - inv);
    float acc = 0.f, wsum = 0.f;
    const float* src = tmp + (long)bc * HH * OUT_W;
    for (int k = 0; k < 7; ++k) {
        int ih = i0 + k;
        if (ih < 0 || ih >= HH) continue;
        float wgt = 1.0f - fabsf(sf - (float)ih) / inv;
        if (wgt <= 0.0f) continue;
        acc += wgt * src[(long)ih * OUT_W + ow];
        wsum += wgt;
    }
    out[((long)bc * OUT_H + oh) * OUT_W + ow] = acc / wsum;
}

extern "C" void kernel_launch(void* const* d_in, const int* in_sizes, int n_in,
                              void* d_out, int out_size, void* d_ws, size_t ws_size,
                              hipStream_t stream) {
    const float* pts  = (const float*)d_in[0];
    const float* pose = (const float*)d_in[1];
    const float* extr = (const float*)d_in[2];
    const float* intr = (const float*)d_in[3];
    int B = in_sizes[1] / 16;
    int N = in_sizes[0] / (3 * B);

    char* ws = (char*)d_ws;
    size_t imgSz = (size_t)B * HH * WW;
    float* depth = (float*)ws;                  // B*H*W f32
    int*   nearA = (int*)(ws + imgSz * 4);      // B*H*W i32
    int*   nearB = (int*)(ws + imgSz * 8);      // B*H*W i32
    float* tmp   = (float*)(ws + imgSz * 12);   // B*2*H*OUT_W f32

    hipMemsetAsync(depth, 0, imgSz * sizeof(float), stream);

    dim3 bs(256);
    scatter_k<<<dim3((N + 255) / 256, B), bs, 0, stream>>>(pts, pose, extr, intr, depth, N);

    dim3 g2((WW + 255) / 256, HH, B);
    init_k<<<g2, bs, 0, stream>>>(depth, nearA);

    const int steps[12] = {1, 1024, 512, 256, 128, 64, 32, 16, 8, 4, 2, 1};
    int* cur = nearA; int* nxt = nearB;
    for (int s = 0; s < 12; ++s) {
        int k = steps[s];
        // group dy=-k: passes (-k,-k),(-k,0),(-k,+k)
        jfa3_k<<<g2, bs, 0, stream>>>(cur, nxt, -k, k);
        { int* t2 = cur; cur = nxt; nxt = t2; }
        // group dy=0: passes (0,-k),(0,+k)
        jfa2_k<<<g2, bs, 0, stream>>>(cur, nxt, k);
        { int* t2 = cur; cur = nxt; nxt = t2; }
        // group dy=+k: passes (+k,-k),(+k,0),(+k,+k)
        jfa3_k<<<g2, bs, 0, stream>>>(cur, nxt, +k, k);
        { int* t2 = cur; cur = nxt; nxt = t2; }
    }

    hresize_k<<<dim3((OUT_W + 255) / 256, HH, B), bs, 0, stream>>>(depth, cur, tmp);
    vresize_k<<<dim3((OUT_W + 255) / 256, OUT_H, B * 2), bs, 0, stream>>>(tmp, (float*)d_out);
}